// Round 10
// baseline (1581.754 us; speedup 1.0000x reference)
//
#include <hip/hip_runtime.h>
#include <hip/hip_bf16.h>

// FFT-tiled conv: B=8, IMG=256, CIN=COUT=64, TILE=64, FFT=68, PAD=2.
// Frequency-domain per-tile conv via DFT-as-matmul, Hermitian half-spectrum
// (k2 in [0,35)), direct overlap-add (plain stores interior, atomics on seams).
// All fp32. Register-blocked reduction sweeps in every DFT stage.
//
// Layouts (per 16-tile chunk slot of CHS floats):
//   Y  [nl][k2][r][i][c]      in bufA     ((nl*35+k2)*64+r)*128
//   X  [nl][k1][k2][i][c]     in bufB     ((nl*68+k1)*35+k2)*128
//   K_t[bin][i][o][c]         78 MB, one-time (bin = k1*35+k2)
//   O  [nl][k2][k1][o][c]     in bufA     ((nl*35+k2)*68+k1)*128
//   Z  [nl][p][k2][o][c]      in bufB     ((nl*68+p)*35+k2)*128
//
// Twiddle tables (zero-padded for fixed-trip register blocking):
//   Wf  [72][64] cplx   rows 68..71 zero      (9216 floats)
//   Wi2 [2][40][68] cplx rows pl=34..39 zero  (10880 floats)
//   Wg  [68][35] cplx                          (4760 floats)

#define KH   35
#define CHS  4874240ull                       // floats per chunk slot
#define KT_FLOATS (68ull * KH * 64 * 64 * 2)  // 19,496,960
#define WS_HEAD 24856ull                      // 9216 + 10880 + 4760

__global__ void k_twiddle(float* ws) {
    const float TWO_PI = 6.28318530717958647692f;
    int t = threadIdx.x;
    float* Wf = ws;                       // 72 x 64 cplx
    for (int e = t; e < 72 * 64; e += 256) {
        int k = e >> 6, m = e & 63;
        float vr = 0.f, vi = 0.f;
        if (k < 68) {
            int ph = (k * (m + 2)) % 68;
            float a = TWO_PI * (float)ph / 68.0f;
            vr = cosf(a); vi = -sinf(a);
        }
        Wf[2 * e] = vr; Wf[2 * e + 1] = vi;
    }
    float* Wi2 = ws + 9216;               // 2 x 40 x 68 cplx
    for (int e = t; e < 2 * 40 * 68; e += 256) {
        int hp = e / 2720, rem2 = e % 2720;
        int pl = rem2 / 68, k = rem2 % 68;
        float vr = 0.f, vi = 0.f;
        if (pl < 34) {
            int p = hp * 34 + pl;
            int ph = (p * k) % 68;
            float a = TWO_PI * (float)ph / 68.0f;
            vr = cosf(a) / 68.0f; vi = sinf(a) / 68.0f;
        }
        Wi2[2 * e] = vr; Wi2[2 * e + 1] = vi;
    }
    float* Wg = ws + 20096;               // 68 x 35 cplx
    for (int e = t; e < 68 * KH; e += 256) {
        int q = e / KH, k2 = e % KH;
        int ph = (q * k2) % 68;
        float a = TWO_PI * (float)ph / 68.0f;
        float alpha = (k2 == 0 || k2 == 34) ? 1.0f : 2.0f;
        Wg[2 * e]     = alpha * cosf(a) / 68.0f;
        Wg[2 * e + 1] = alpha * sinf(a) / 68.0f;
    }
}

__global__ void k_zero(float* out, int n) {
    int idx = blockIdx.x * 256 + threadIdx.x;
    float4* o4 = (float4*)out;
    for (int i = idx; i < n / 4; i += gridDim.x * 256) o4[i] = make_float4(0, 0, 0, 0);
}

// ---------- one-time kernel-spectrum transpose: K_t[bin][i][o][c] ----------
__global__ void k_ktrans(const float* __restrict__ kr, const float* __restrict__ ki,
                         float* __restrict__ Kt) {
    __shared__ float tr[64 * 37];
    __shared__ float ti[64 * 37];
    int k1 = blockIdx.x >> 6, i = blockIdx.x & 63;
    int t = threadIdx.x;
    for (int e = t; e < 64 * KH; e += 256) {
        int o = e / KH, k2 = e % KH;
        size_t src = ((size_t)(o * 64 + i) * 68 + k1) * 68 + k2;
        tr[o * 37 + k2] = kr[src];
        ti[o * 37 + k2] = ki[src];
    }
    __syncthreads();
    for (int e = t; e < KH * 64; e += 256) {
        int k2 = e >> 6, o = e & 63;
        size_t dst = ((size_t)(k1 * KH + k2)) * 8192 + (size_t)i * 128 + o * 2;
        Kt[dst]     = tr[o * 37 + k2];
        Kt[dst + 1] = ti[o * 37 + k2];
    }
}

// ---------------- stage 1: row DFT ----------------
// Y[nl][k2][r][i] = sum_c x[b, tr*64+r, tc*64+c, i] * Wf[k2][c]
__global__ void k_fwd_row(const float* __restrict__ x, const float* __restrict__ Wf,
                          float* __restrict__ Y, int c0) {
    __shared__ float xr[64 * 64];        // [c][i]
    __shared__ float wf[KH * 64 * 2];    // [k2][c]
    __shared__ float yout[KH * 128];     // [k2][i][c]
    int lc = blockIdx.x >> 10;
    int rem = blockIdx.x & 1023;
    int nl = rem >> 6, r = rem & 63;
    int n = (c0 + lc) * 16 + nl;
    int b = n >> 4, tr = (n >> 2) & 3, tc = n & 3;
    const float* src = x + (((size_t)(b * 256 + tr * 64 + r)) * 256 + tc * 64) * 64;
    int t = threadIdx.x;
    const float4* src4 = (const float4*)src;
    float4* xr4 = (float4*)xr;
    for (int e = t; e < 1024; e += 256) xr4[e] = src4[e];
    for (int e = t; e < KH * 64 * 2; e += 256) wf[e] = Wf[e];
    __syncthreads();
    int i = t & 63, kg = t >> 6;
    for (int k2 = kg; k2 < KH; k2 += 4) {
        float ar = 0.f, ai = 0.f;
        const float* w = wf + k2 * 128;
        for (int c = 0; c < 64; ++c) {
            float v = xr[(c << 6) | i];
            ar += v * w[2 * c];
            ai += v * w[2 * c + 1];
        }
        yout[(k2 << 7) + 2 * i]     = ar;
        yout[(k2 << 7) + 2 * i + 1] = ai;
    }
    __syncthreads();
    float* Yc = Y + (size_t)lc * CHS;
    const float4* ys4 = (const float4*)yout;
    for (int e = t; e < KH * 32; e += 256) {
        int k2 = e >> 5, f = e & 31;
        ((float4*)(Yc + ((size_t)(nl * KH + k2) * 64 + r) * 128))[f] = ys4[e];
    }
}

// ---------------- stage 2: column DFT (register-blocked k1 sweep) ----------
// X[nl][k1][k2][i] = sum_r Wf[k1][r] * Y[nl][k2][r][i]
// thread (i, g): 9 k1-accumulators (k1 = g+8j), one r-sweep, zv read once/r.
__global__ __launch_bounds__(512) void k_fwd_col(
        const float* __restrict__ Y, const float* __restrict__ Wf,
        float* __restrict__ X) {
    __shared__ float yl[64 * 128];       // 32 KB [r][i][c]
    int lc = blockIdx.x / 560;
    int rem = blockIdx.x % 560;
    int nl = rem / KH, k2 = rem % KH;
    const float* Yc = Y + (size_t)lc * CHS + ((size_t)(nl * KH + k2)) * 8192;
    float* Xc = X + (size_t)lc * CHS;
    int t = threadIdx.x;
    float4* yl4 = (float4*)yl;
    const float4* ys4 = (const float4*)Yc;
    for (int e = t; e < 2048; e += 512) yl4[e] = ys4[e];
    __syncthreads();
    int i = t & 63, g = t >> 6;          // wave-uniform g
    float ar[9], ai[9];
    #pragma unroll
    for (int j = 0; j < 9; ++j) { ar[j] = 0.f; ai[j] = 0.f; }
    const float* zr = yl + 2 * i;
    #pragma unroll 4
    for (int r = 0; r < 64; ++r) {
        float2 zv = *(const float2*)(zr + (r << 7));
        const float* wp = Wf + 2 * ((g << 6) + r);   // wave-uniform -> s_load
        #pragma unroll
        for (int j = 0; j < 9; ++j) {
            float2 wv = *(const float2*)(wp + j * 1024);  // rows 68..71 are zero
            ar[j] += wv.x * zv.x - wv.y * zv.y;
            ai[j] += wv.x * zv.y + wv.y * zv.x;
        }
    }
    #pragma unroll
    for (int j = 0; j < 9; ++j) {
        int k1 = g + 8 * j;
        if (k1 < 68)
            *(float2*)(Xc + ((size_t)(nl * 68 + k1) * KH + k2) * 128 + 2 * i)
                = make_float2(ar[j], ai[j]);
    }
}

// ---------------- stage 3: per-bin channel mix (2o x 2n register tile) -----
// O[nl][k2][k1][o] = sum_i X[nl][k1][k2][i] * K[bin][i][o]
__global__ void k_mix(const float* __restrict__ X, const float* __restrict__ Kt,
                      const float* __restrict__ kr, const float* __restrict__ ki,
                      float* __restrict__ O, int useKt) {
    __shared__ float xl[16 * 128];       // [n][i][c]  8 KB
    __shared__ float kl[64 * 64 * 2];    // [i][o][c] 32 KB
    int lc = blockIdx.x / 2380;
    int bin = blockIdx.x % 2380;
    int k1 = bin / KH, k2 = bin % KH;
    const float* Xc = X + (size_t)lc * CHS;
    float* Oc = O + (size_t)lc * CHS;
    int t = threadIdx.x;
    for (int e = t; e < 2048; e += 256) {
        int n = e >> 7, ic = e & 127;
        xl[e] = Xc[((size_t)(n * 68 + k1) * KH + k2) * 128 + ic];
    }
    if (useKt) {
        const float* src = Kt + (size_t)bin * 8192;
        for (int e = t; e < 8192; e += 256) kl[e] = src[e];
    } else {
        for (int e = t; e < 4096; e += 256) {
            int o = e >> 6, i = e & 63;
            size_t gi = ((size_t)(o * 64 + i) * 68 + k1) * 68 + k2;
            kl[i * 128 + o * 2]     = kr[gi];
            kl[i * 128 + o * 2 + 1] = ki[gi];
        }
    }
    __syncthreads();
    int op = t & 31, g = t >> 5;         // o = 2op,2op+1 ; n = g, g+8
    float a0r=0,a0i=0,a1r=0,a1i=0,b0r=0,b0i=0,b1r=0,b1i=0;
    for (int i = 0; i < 64; ++i) {
        float4 kv = *(const float4*)(kl + i * 128 + op * 4);
        float2 c0 = *(const float2*)(xl + (g << 7) + i * 2);
        float2 c1 = *(const float2*)(xl + ((g + 8) << 7) + i * 2);
        a0r += kv.x * c0.x - kv.y * c0.y;  a0i += kv.x * c0.y + kv.y * c0.x;
        a1r += kv.z * c0.x - kv.w * c0.y;  a1i += kv.z * c0.y + kv.w * c0.x;
        b0r += kv.x * c1.x - kv.y * c1.y;  b0i += kv.x * c1.y + kv.y * c1.x;
        b1r += kv.z * c1.x - kv.w * c1.y;  b1i += kv.z * c1.y + kv.w * c1.x;
    }
    size_t base0 = ((((size_t)g       * KH + k2) * 68 + k1) * 64 + 2 * op) * 2;
    size_t base1 = ((((size_t)(g + 8) * KH + k2) * 68 + k1) * 64 + 2 * op) * 2;
    *(float4*)(Oc + base0) = make_float4(a0r, a0i, a1r, a1i);
    *(float4*)(Oc + base1) = make_float4(b0r, b0i, b1r, b1i);
}

// ---------------- stage 4: inverse column DFT (register-blocked p sweep) ----
// Z[nl][p][k2][o] = sum_k1 Wi[p][k1] * O[nl][k2][k1][o]
// thread (o, g): 5 p-accumulators (pl = g+8j), one k1-sweep, ov read once/k1.
__global__ __launch_bounds__(512) void k_inv_col(
        const float* __restrict__ O, const float* __restrict__ Wi2,
        float* __restrict__ Z) {
    __shared__ float ol[68 * 128];       // 34 KB
    int lc = blockIdx.x / 1120;
    int rem = blockIdx.x % 1120;
    int ph = rem & 1;
    int rest = rem >> 1;
    int k2 = rest % KH, nl = rest / KH;
    int t = threadIdx.x;
    const float* Oc = O + (size_t)lc * CHS;
    float* Zc = Z + (size_t)lc * CHS;
    const float4* osrc = (const float4*)(Oc + ((size_t)nl * KH + k2) * 68 * 128);
    float4* ol4 = (float4*)ol;
    for (int e = t; e < 68 * 32; e += 512) ol4[e] = osrc[e];
    __syncthreads();
    int o = t & 63, g = t >> 6;          // wave-uniform g
    float ar[5], ai[5];
    #pragma unroll
    for (int j = 0; j < 5; ++j) { ar[j] = 0.f; ai[j] = 0.f; }
    const float* oo_ = ol + 2 * o;
    const float* wbase = Wi2 + (size_t)(ph * 40 + g) * 136;  // wave-uniform
    #pragma unroll 4
    for (int k1 = 0; k1 < 68; ++k1) {
        float2 ov = *(const float2*)(oo_ + (k1 << 7));
        const float* wp = wbase + 2 * k1;
        #pragma unroll
        for (int j = 0; j < 5; ++j) {
            float2 wv = *(const float2*)(wp + j * 1088);  // rows pl>=34 are zero
            ar[j] += wv.x * ov.x - wv.y * ov.y;
            ai[j] += wv.x * ov.y + wv.y * ov.x;
        }
    }
    #pragma unroll
    for (int j = 0; j < 5; ++j) {
        int pl = g + 8 * j;
        if (pl < 34) {
            int p = ph * 34 + pl;
            *(float2*)(Zc + ((size_t)(nl * 68 + p) * KH + k2) * 128 + 2 * o)
                = make_float2(ar[j], ai[j]);
        }
    }
}

// ---------------- stage 5: inverse row DFT + overlap-add --------------------
__global__ __launch_bounds__(256) void k_fused_inv(
        const float* __restrict__ Z, const float* __restrict__ Wg,
        const float* __restrict__ bias, float* __restrict__ out, int c0) {
    __shared__ float zl[KH * 128];       // 17.9 KB [k2][o][c]
    __shared__ float wg[68 * 70];        // 19.0 KB [q][k2c]
    int lc = blockIdx.x / 1088;
    int rem = blockIdx.x % 1088;
    int nl = rem / 68, p = rem % 68;
    int b = c0 + lc;
    int tr = nl >> 2, tc = nl & 3;
    int y = 66 * tr + p;
    if (y >= 256) return;
    int t = threadIdx.x;
    const float4* zs4 = (const float4*)(Z + (size_t)lc * CHS
                                        + ((size_t)(nl * 68 + p)) * 4480);
    float4* zl4 = (float4*)zl;
    for (int e = t; e < 1120; e += 256) zl4[e] = zs4[e];
    for (int e = t; e < 4760; e += 256) wg[e] = Wg[e];
    __syncthreads();

    int o = t & 63, qg = t >> 6;         // qg in 0..3, q = qg*17 + j
    float bv = bias[o];
    const float* zr = zl + 2 * o;
    const float* wbase = wg + (qg * 17) * 70;

    float acc[17];
    #pragma unroll
    for (int j = 0; j < 17; ++j) acc[j] = 0.f;

    for (int k2 = 0; k2 < KH; ++k2) {
        float2 zv = *(const float2*)(zr + (k2 << 7));
        #pragma unroll
        for (int j = 0; j < 17; ++j) {
            float2 wv = *(const float2*)(wbase + j * 70 + 2 * k2);  // broadcast
            acc[j] += zv.x * wv.x - zv.y * wv.y;
        }
    }

    bool rowu = !((p <= 1 && tr > 0) || (p >= 66 && tr < 3));
    float* orow = out + ((size_t)(b * 256 + y)) * 256 * 64 + o;
    #pragma unroll
    for (int j = 0; j < 17; ++j) {
        int q = qg * 17 + j;
        int x = 66 * tc + q;
        if (x >= 256) continue;
        bool colu = !((q <= 1 && tc > 0) || (q >= 66 && tc < 3));
        float v = acc[j] + bv;
        if (rowu && colu) orow[(size_t)x * 64] = v;
        else              atomicAdd(orow + (size_t)x * 64, v);
    }
}

extern "C" void kernel_launch(void* const* d_in, const int* in_sizes, int n_in,
                              void* d_out, int out_size, void* d_ws, size_t ws_size,
                              hipStream_t stream) {
    const float* x    = (const float*)d_in[0];
    const float* kr   = (const float*)d_in[1];
    const float* ki   = (const float*)d_in[2];
    const float* bias = (const float*)d_in[3];
    float* out = (float*)d_out;
    float* ws  = (float*)d_ws;

    int useKt = 1;
    int CH = 8;
    while (CH > 1 && (WS_HEAD + KT_FLOATS + 2ull * CH * CHS) * 4ull > ws_size) CH >>= 1;
    if ((WS_HEAD + KT_FLOATS + 2ull * CH * CHS) * 4ull > ws_size) {
        useKt = 0;
        CH = 8;
        while (CH > 1 && (WS_HEAD + 2ull * CH * CHS) * 4ull > ws_size) CH >>= 1;
    }

    float* Wf   = ws;                          // 9216 floats (72x64 cplx, padded)
    float* Wi2  = ws + 9216;                   // 10880 floats (2x40x68 cplx, padded)
    float* Wg   = ws + 20096;                  // 4760 floats
    float* Kt   = ws + WS_HEAD;                // KT_FLOATS (if useKt)
    float* bufA = Kt + (useKt ? KT_FLOATS : 0);   // Y then O
    float* bufB = bufA + (size_t)CH * CHS;        // X then Z

    k_twiddle<<<1, 256, 0, stream>>>(ws);
    if (useKt)
        k_ktrans<<<68 * 64, 256, 0, stream>>>(kr, ki, Kt);
    k_zero<<<2048, 256, 0, stream>>>(out, 8 * 256 * 256 * 64);

    for (int s = 0; s < 8; s += CH) {
        k_fwd_row<<<CH * 1024, 256, 0, stream>>>(x, Wf, bufA, s);
        k_fwd_col<<<CH * 560, 512, 0, stream>>>(bufA, Wf, bufB);
        k_mix<<<CH * 2380, 256, 0, stream>>>(bufB, Kt, kr, ki, bufA, useKt);
        k_inv_col<<<CH * 1120, 512, 0, stream>>>(bufA, Wi2, bufB);
        k_fused_inv<<<CH * 1088, 256, 0, stream>>>(bufB, Wg, bias, out, s);
    }
}

// Round 11
// 1360.075 us; speedup vs baseline: 1.1630x; 1.1630x over previous
//
#include <hip/hip_runtime.h>
#include <hip/hip_bf16.h>

// FFT-tiled conv: B=8, IMG=256, CIN=COUT=64, TILE=64, FFT=68, PAD=2.
// Frequency-domain per-tile conv via DFT-as-matmul, Hermitian half-spectrum
// (k2 in [0,35)), direct overlap-add (plain stores interior, atomics on seams).
// All fp32. Register-blocked reduction sweeps; twiddles broadcast from LDS.
//
// Layouts (per 16-tile chunk slot of CHS floats):
//   Y  [nl][k2][r][i][c]      in bufA     ((nl*35+k2)*64+r)*128
//   X  [nl][k1][k2][i][c]     in bufB     ((nl*68+k1)*35+k2)*128
//   K_t[bin][i][o][c]         78 MB, one-time (bin = k1*35+k2)
//   O  [nl][k2][k1][o][c]     in bufA     ((nl*35+k2)*68+k1)*128
//   Z  [nl][p][k2][o][c]      in bufB     ((nl*68+p)*35+k2)*128
//
// Twiddle tables (zero-padded for fixed-trip register blocking):
//   Wf  [72][64] cplx   rows 68..71 zero      (9216 floats)
//   Wi2 [2][40][68] cplx rows pl=34..39 zero  (10880 floats)
//   Wg  [68][35] cplx                          (4760 floats)

#define KH   35
#define CHS  4874240ull                       // floats per chunk slot
#define KT_FLOATS (68ull * KH * 64 * 64 * 2)  // 19,496,960
#define WS_HEAD 24856ull                      // 9216 + 10880 + 4760

__global__ void k_twiddle(float* ws) {
    const float TWO_PI = 6.28318530717958647692f;
    int t = threadIdx.x;
    float* Wf = ws;                       // 72 x 64 cplx
    for (int e = t; e < 72 * 64; e += 256) {
        int k = e >> 6, m = e & 63;
        float vr = 0.f, vi = 0.f;
        if (k < 68) {
            int ph = (k * (m + 2)) % 68;
            float a = TWO_PI * (float)ph / 68.0f;
            vr = cosf(a); vi = -sinf(a);
        }
        Wf[2 * e] = vr; Wf[2 * e + 1] = vi;
    }
    float* Wi2 = ws + 9216;               // 2 x 40 x 68 cplx
    for (int e = t; e < 2 * 40 * 68; e += 256) {
        int hp = e / 2720, rem2 = e % 2720;
        int pl = rem2 / 68, k = rem2 % 68;
        float vr = 0.f, vi = 0.f;
        if (pl < 34) {
            int p = hp * 34 + pl;
            int ph = (p * k) % 68;
            float a = TWO_PI * (float)ph / 68.0f;
            vr = cosf(a) / 68.0f; vi = sinf(a) / 68.0f;
        }
        Wi2[2 * e] = vr; Wi2[2 * e + 1] = vi;
    }
    float* Wg = ws + 20096;               // 68 x 35 cplx
    for (int e = t; e < 68 * KH; e += 256) {
        int q = e / KH, k2 = e % KH;
        int ph = (q * k2) % 68;
        float a = TWO_PI * (float)ph / 68.0f;
        float alpha = (k2 == 0 || k2 == 34) ? 1.0f : 2.0f;
        Wg[2 * e]     = alpha * cosf(a) / 68.0f;
        Wg[2 * e + 1] = alpha * sinf(a) / 68.0f;
    }
}

__global__ void k_zero(float* out, int n) {
    int idx = blockIdx.x * 256 + threadIdx.x;
    float4* o4 = (float4*)out;
    for (int i = idx; i < n / 4; i += gridDim.x * 256) o4[i] = make_float4(0, 0, 0, 0);
}

// ---------- one-time kernel-spectrum transpose: K_t[bin][i][o][c] ----------
__global__ void k_ktrans(const float* __restrict__ kr, const float* __restrict__ ki,
                         float* __restrict__ Kt) {
    __shared__ float tr[64 * 37];
    __shared__ float ti[64 * 37];
    int k1 = blockIdx.x >> 6, i = blockIdx.x & 63;
    int t = threadIdx.x;
    for (int e = t; e < 64 * KH; e += 256) {
        int o = e / KH, k2 = e % KH;
        size_t src = ((size_t)(o * 64 + i) * 68 + k1) * 68 + k2;
        tr[o * 37 + k2] = kr[src];
        ti[o * 37 + k2] = ki[src];
    }
    __syncthreads();
    for (int e = t; e < KH * 64; e += 256) {
        int k2 = e >> 6, o = e & 63;
        size_t dst = ((size_t)(k1 * KH + k2)) * 8192 + (size_t)i * 128 + o * 2;
        Kt[dst]     = tr[o * 37 + k2];
        Kt[dst + 1] = ti[o * 37 + k2];
    }
}

// ---------------- stage 1: row DFT ----------------
// Y[nl][k2][r][i] = sum_c x[b, tr*64+r, tc*64+c, i] * Wf[k2][c]
__global__ void k_fwd_row(const float* __restrict__ x, const float* __restrict__ Wf,
                          float* __restrict__ Y, int c0) {
    __shared__ float xr[64 * 64];        // [c][i]
    __shared__ float wf[KH * 64 * 2];    // [k2][c]
    __shared__ float yout[KH * 128];     // [k2][i][c]
    int lc = blockIdx.x >> 10;
    int rem = blockIdx.x & 1023;
    int nl = rem >> 6, r = rem & 63;
    int n = (c0 + lc) * 16 + nl;
    int b = n >> 4, tr = (n >> 2) & 3, tc = n & 3;
    const float* src = x + (((size_t)(b * 256 + tr * 64 + r)) * 256 + tc * 64) * 64;
    int t = threadIdx.x;
    const float4* src4 = (const float4*)src;
    float4* xr4 = (float4*)xr;
    for (int e = t; e < 1024; e += 256) xr4[e] = src4[e];
    for (int e = t; e < KH * 64 * 2; e += 256) wf[e] = Wf[e];
    __syncthreads();
    int i = t & 63, kg = t >> 6;
    for (int k2 = kg; k2 < KH; k2 += 4) {
        float ar = 0.f, ai = 0.f;
        const float* w = wf + k2 * 128;
        for (int c = 0; c < 64; ++c) {
            float v = xr[(c << 6) | i];
            ar += v * w[2 * c];
            ai += v * w[2 * c + 1];
        }
        yout[(k2 << 7) + 2 * i]     = ar;
        yout[(k2 << 7) + 2 * i + 1] = ai;
    }
    __syncthreads();
    float* Yc = Y + (size_t)lc * CHS;
    const float4* ys4 = (const float4*)yout;
    for (int e = t; e < KH * 32; e += 256) {
        int k2 = e >> 5, f = e & 31;
        ((float4*)(Yc + ((size_t)(nl * KH + k2) * 64 + r) * 128))[f] = ys4[e];
    }
}

// ---------------- stage 2: column DFT (reg-blocked k1 sweep, LDS twiddles) --
// X[nl][k1][k2][i] = sum_r Wf[k1][r] * Y[nl][k2][r][i]
// thread (i, g): 9 k1-accumulators (k1 = g+8j), one r-sweep;
// zv: one LDS b64/r (lane-varying); wv: broadcast LDS b64 (wave-uniform addr).
__global__ __launch_bounds__(512) void k_fwd_col(
        const float* __restrict__ Y, const float* __restrict__ Wf,
        float* __restrict__ X) {
    __shared__ float yl[64 * 128];       // 32 KB   [r][i][c]
    __shared__ float wfs[72 * 128];      // 36.9 KB [k1][r][c] (padded rows zero)
    int lc = blockIdx.x / 560;
    int rem = blockIdx.x % 560;
    int nl = rem / KH, k2 = rem % KH;
    const float* Yc = Y + (size_t)lc * CHS + ((size_t)(nl * KH + k2)) * 8192;
    float* Xc = X + (size_t)lc * CHS;
    int t = threadIdx.x;
    float4* yl4 = (float4*)yl;
    const float4* ys4 = (const float4*)Yc;
    for (int e = t; e < 2048; e += 512) yl4[e] = ys4[e];
    float4* wf4 = (float4*)wfs;
    const float4* wsrc4 = (const float4*)Wf;
    for (int e = t; e < 2304; e += 512) wf4[e] = wsrc4[e];
    __syncthreads();
    int i = t & 63, g = t >> 6;          // wave-uniform g
    float ar[9], ai[9];
    #pragma unroll
    for (int j = 0; j < 9; ++j) { ar[j] = 0.f; ai[j] = 0.f; }
    const float* zr = yl + 2 * i;
    const float* wb = wfs + (g << 7);    // wave-uniform base
    #pragma unroll 4
    for (int r = 0; r < 64; ++r) {
        float2 zv = *(const float2*)(zr + (r << 7));
        #pragma unroll
        for (int j = 0; j < 9; ++j) {
            float2 wv = *(const float2*)(wb + j * 1024 + 2 * r);  // broadcast
            ar[j] += wv.x * zv.x - wv.y * zv.y;
            ai[j] += wv.x * zv.y + wv.y * zv.x;
        }
    }
    #pragma unroll
    for (int j = 0; j < 9; ++j) {
        int k1 = g + 8 * j;
        if (k1 < 68)
            *(float2*)(Xc + ((size_t)(nl * 68 + k1) * KH + k2) * 128 + 2 * i)
                = make_float2(ar[j], ai[j]);
    }
}

// ---------------- stage 3: per-bin channel mix (2o x 2n register tile) -----
// O[nl][k2][k1][o] = sum_i X[nl][k1][k2][i] * K[bin][i][o]
__global__ void k_mix(const float* __restrict__ X, const float* __restrict__ Kt,
                      const float* __restrict__ kr, const float* __restrict__ ki,
                      float* __restrict__ O, int useKt) {
    __shared__ float xl[16 * 128];       // [n][i][c]  8 KB
    __shared__ float kl[64 * 64 * 2];    // [i][o][c] 32 KB
    int lc = blockIdx.x / 2380;
    int bin = blockIdx.x % 2380;
    int k1 = bin / KH, k2 = bin % KH;
    const float* Xc = X + (size_t)lc * CHS;
    float* Oc = O + (size_t)lc * CHS;
    int t = threadIdx.x;
    for (int e = t; e < 2048; e += 256) {
        int n = e >> 7, ic = e & 127;
        xl[e] = Xc[((size_t)(n * 68 + k1) * KH + k2) * 128 + ic];
    }
    if (useKt) {
        const float* src = Kt + (size_t)bin * 8192;
        for (int e = t; e < 8192; e += 256) kl[e] = src[e];
    } else {
        for (int e = t; e < 4096; e += 256) {
            int o = e >> 6, i = e & 63;
            size_t gi = ((size_t)(o * 64 + i) * 68 + k1) * 68 + k2;
            kl[i * 128 + o * 2]     = kr[gi];
            kl[i * 128 + o * 2 + 1] = ki[gi];
        }
    }
    __syncthreads();
    int op = t & 31, g = t >> 5;         // o = 2op,2op+1 ; n = g, g+8
    float a0r=0,a0i=0,a1r=0,a1i=0,b0r=0,b0i=0,b1r=0,b1i=0;
    for (int i = 0; i < 64; ++i) {
        float4 kv = *(const float4*)(kl + i * 128 + op * 4);
        float2 c0 = *(const float2*)(xl + (g << 7) + i * 2);
        float2 c1 = *(const float2*)(xl + ((g + 8) << 7) + i * 2);
        a0r += kv.x * c0.x - kv.y * c0.y;  a0i += kv.x * c0.y + kv.y * c0.x;
        a1r += kv.z * c0.x - kv.w * c0.y;  a1i += kv.z * c0.y + kv.w * c0.x;
        b0r += kv.x * c1.x - kv.y * c1.y;  b0i += kv.x * c1.y + kv.y * c1.x;
        b1r += kv.z * c1.x - kv.w * c1.y;  b1i += kv.z * c1.y + kv.w * c1.x;
    }
    size_t base0 = ((((size_t)g       * KH + k2) * 68 + k1) * 64 + 2 * op) * 2;
    size_t base1 = ((((size_t)(g + 8) * KH + k2) * 68 + k1) * 64 + 2 * op) * 2;
    *(float4*)(Oc + base0) = make_float4(a0r, a0i, a1r, a1i);
    *(float4*)(Oc + base1) = make_float4(b0r, b0i, b1r, b1i);
}

// ---------------- stage 4: inverse col DFT (reg-blocked p sweep, LDS tw) ----
// Z[nl][p][k2][o] = sum_k1 Wi[p][k1] * O[nl][k2][k1][o]
// thread (o, g): 5 p-accumulators (pl = g+8j), one k1-sweep;
// ov: one LDS b64/k1; wv: broadcast LDS b64 from staged Wi2 half.
__global__ __launch_bounds__(512) void k_inv_col(
        const float* __restrict__ O, const float* __restrict__ Wi2,
        float* __restrict__ Z) {
    __shared__ float ol[68 * 128];       // 34 KB   [k1][o][c]
    __shared__ float wih[40 * 136];      // 21.8 KB [pl][k1][c] (padded rows zero)
    int lc = blockIdx.x / 1120;
    int rem = blockIdx.x % 1120;
    int ph = rem & 1;
    int rest = rem >> 1;
    int k2 = rest % KH, nl = rest / KH;
    int t = threadIdx.x;
    const float* Oc = O + (size_t)lc * CHS;
    float* Zc = Z + (size_t)lc * CHS;
    const float4* osrc = (const float4*)(Oc + ((size_t)nl * KH + k2) * 68 * 128);
    float4* ol4 = (float4*)ol;
    for (int e = t; e < 68 * 32; e += 512) ol4[e] = osrc[e];
    const float4* wsrc4 = (const float4*)(Wi2 + (size_t)ph * 5440);
    float4* wi4 = (float4*)wih;
    for (int e = t; e < 1360; e += 512) wi4[e] = wsrc4[e];
    __syncthreads();
    int o = t & 63, g = t >> 6;          // wave-uniform g
    float ar[5], ai[5];
    #pragma unroll
    for (int j = 0; j < 5; ++j) { ar[j] = 0.f; ai[j] = 0.f; }
    const float* oo_ = ol + 2 * o;
    const float* wb = wih + g * 136;     // wave-uniform base
    #pragma unroll 4
    for (int k1 = 0; k1 < 68; ++k1) {
        float2 ov = *(const float2*)(oo_ + (k1 << 7));
        #pragma unroll
        for (int j = 0; j < 5; ++j) {
            float2 wv = *(const float2*)(wb + j * 1088 + 2 * k1);  // broadcast
            ar[j] += wv.x * ov.x - wv.y * ov.y;
            ai[j] += wv.x * ov.y + wv.y * ov.x;
        }
    }
    #pragma unroll
    for (int j = 0; j < 5; ++j) {
        int pl = g + 8 * j;
        if (pl < 34) {
            int p = ph * 34 + pl;
            *(float2*)(Zc + ((size_t)(nl * 68 + p) * KH + k2) * 128 + 2 * o)
                = make_float2(ar[j], ai[j]);
        }
    }
}

// ---------------- stage 5: inverse row DFT + overlap-add --------------------
__global__ __launch_bounds__(256) void k_fused_inv(
        const float* __restrict__ Z, const float* __restrict__ Wg,
        const float* __restrict__ bias, float* __restrict__ out, int c0) {
    __shared__ float zl[KH * 128];       // 17.9 KB [k2][o][c]
    __shared__ float wg[68 * 70];        // 19.0 KB [q][k2c]
    int lc = blockIdx.x / 1088;
    int rem = blockIdx.x % 1088;
    int nl = rem / 68, p = rem % 68;
    int b = c0 + lc;
    int tr = nl >> 2, tc = nl & 3;
    int y = 66 * tr + p;
    if (y >= 256) return;
    int t = threadIdx.x;
    const float4* zs4 = (const float4*)(Z + (size_t)lc * CHS
                                        + ((size_t)(nl * 68 + p)) * 4480);
    float4* zl4 = (float4*)zl;
    for (int e = t; e < 1120; e += 256) zl4[e] = zs4[e];
    for (int e = t; e < 4760; e += 256) wg[e] = Wg[e];
    __syncthreads();

    int o = t & 63, qg = t >> 6;         // qg in 0..3, q = qg*17 + j
    float bv = bias[o];
    const float* zr = zl + 2 * o;
    const float* wbase = wg + (qg * 17) * 70;

    float acc[17];
    #pragma unroll
    for (int j = 0; j < 17; ++j) acc[j] = 0.f;

    for (int k2 = 0; k2 < KH; ++k2) {
        float2 zv = *(const float2*)(zr + (k2 << 7));
        #pragma unroll
        for (int j = 0; j < 17; ++j) {
            float2 wv = *(const float2*)(wbase + j * 70 + 2 * k2);  // broadcast
            acc[j] += zv.x * wv.x - zv.y * wv.y;
        }
    }

    bool rowu = !((p <= 1 && tr > 0) || (p >= 66 && tr < 3));
    float* orow = out + ((size_t)(b * 256 + y)) * 256 * 64 + o;
    #pragma unroll
    for (int j = 0; j < 17; ++j) {
        int q = qg * 17 + j;
        int x = 66 * tc + q;
        if (x >= 256) continue;
        bool colu = !((q <= 1 && tc > 0) || (q >= 66 && tc < 3));
        float v = acc[j] + bv;
        if (rowu && colu) orow[(size_t)x * 64] = v;
        else              atomicAdd(orow + (size_t)x * 64, v);
    }
}

extern "C" void kernel_launch(void* const* d_in, const int* in_sizes, int n_in,
                              void* d_out, int out_size, void* d_ws, size_t ws_size,
                              hipStream_t stream) {
    const float* x    = (const float*)d_in[0];
    const float* kr   = (const float*)d_in[1];
    const float* ki   = (const float*)d_in[2];
    const float* bias = (const float*)d_in[3];
    float* out = (float*)d_out;
    float* ws  = (float*)d_ws;

    int useKt = 1;
    int CH = 8;
    while (CH > 1 && (WS_HEAD + KT_FLOATS + 2ull * CH * CHS) * 4ull > ws_size) CH >>= 1;
    if ((WS_HEAD + KT_FLOATS + 2ull * CH * CHS) * 4ull > ws_size) {
        useKt = 0;
        CH = 8;
        while (CH > 1 && (WS_HEAD + 2ull * CH * CHS) * 4ull > ws_size) CH >>= 1;
    }

    float* Wf   = ws;                          // 9216 floats (72x64 cplx, padded)
    float* Wi2  = ws + 9216;                   // 10880 floats (2x40x68 cplx, padded)
    float* Wg   = ws + 20096;                  // 4760 floats
    float* Kt   = ws + WS_HEAD;                // KT_FLOATS (if useKt)
    float* bufA = Kt + (useKt ? KT_FLOATS : 0);   // Y then O
    float* bufB = bufA + (size_t)CH * CHS;        // X then Z

    k_twiddle<<<1, 256, 0, stream>>>(ws);
    if (useKt)
        k_ktrans<<<68 * 64, 256, 0, stream>>>(kr, ki, Kt);
    k_zero<<<2048, 256, 0, stream>>>(out, 8 * 256 * 256 * 64);

    for (int s = 0; s < 8; s += CH) {
        k_fwd_row<<<CH * 1024, 256, 0, stream>>>(x, Wf, bufA, s);
        k_fwd_col<<<CH * 560, 512, 0, stream>>>(bufA, Wf, bufB);
        k_mix<<<CH * 2380, 256, 0, stream>>>(bufB, Kt, kr, ki, bufA, useKt);
        k_inv_col<<<CH * 1120, 512, 0, stream>>>(bufA, Wi2, bufB);
        k_fused_inv<<<CH * 1088, 256, 0, stream>>>(bufB, Wg, bias, out, s);
    }
}